// Round 1
// baseline (166.172 us; speedup 1.0000x reference)
//
#include <hip/hip_runtime.h>

// Lucas-Kanade optical flow, fully fused single kernel.
// H=W=2048, window 15 (radius 7), f32 in/out.

constexpr int IH  = 2048;
constexpr int IW  = 2048;
constexpr int RAD = 7;
constexpr int WIN = 15;
constexpr int SW  = 128;            // output columns per block (== blockDim.x)
constexpr int RB  = 32;             // output rows per block
constexpr int BT  = 128;            // threads per block
constexpr int NC  = SW + WIN - 1;   // 142 product columns per block
constexpr int NIC = NC + 2;         // 144 image columns staged

__global__ __launch_bounds__(BT)
void lk_fused_kernel(const float* __restrict__ prev,
                     const float* __restrict__ nxt,
                     float* __restrict__ out) {
    const int tid = threadIdx.x;
    const int c0  = blockIdx.x * SW;
    const int r0  = blockIdx.y * RB;
    const int x   = c0 + tid;                // this thread's output column

    __shared__ float s_rowA[2][NIC];         // [img][col] row pr
    __shared__ float s_rowB[2][NIC];         // [img][col] row pr+1
    __shared__ float s_prow[5][NC];          // products of current scan row
    __shared__ float s_ring[WIN][5][SW];     // horizontal-sum history ring

    // zero the ring (csum starts at 0; subtracting zeros during warmup is correct)
    for (int idx = tid; idx < WIN * 5 * SW; idx += BT)
        (&s_ring[0][0][0])[idx] = 0.f;

    float a0 = 0.f, a1 = 0.f, a2 = 0.f, a3 = 0.f, a4 = 0.f; // Axx,Axy,Ayy,bx,by

    __syncthreads();

    for (int sr = 0; sr < RB + WIN - 1; ++sr) {
        const int pr = r0 - RAD + sr;        // product row being scanned

        // ---- stage image rows pr and pr+1 (clamped addresses; values for
        //      pr<0 / pr>=IH are unused because products are gated to 0) ----
        const int ra = pr < 0 ? 0 : (pr >= IH ? IH - 1 : pr);
        const int rb = (pr + 1) < 0 ? 0 : ((pr + 1) >= IH ? IH - 1 : pr + 1);
        for (int c = tid; c < NIC; c += BT) {
            int gc = c0 - RAD + c;
            gc = gc < 0 ? 0 : (gc >= IW ? IW - 1 : gc);
            s_rowA[0][c] = prev[ra * IW + gc];
            s_rowB[0][c] = prev[rb * IW + gc];
            s_rowA[1][c] = nxt[ra * IW + gc];
            s_rowB[1][c] = nxt[rb * IW + gc];
        }
        __syncthreads();

        // ---- derivative products for this row (zero outside image: box
        //      filter is zero-padded; clamped staging gives the derivative's
        //      bottom/right edge replication) ----
        const bool row_ok = (pr >= 0) && (pr < IH);
        for (int ci = tid; ci < NC; ci += BT) {
            const int pc = c0 - RAD + ci;
            float q0 = 0.f, q1 = 0.f, q2 = 0.f, q3 = 0.f, q4 = 0.f;
            if (row_ok && pc >= 0 && pc < IW) {
                const float p00 = s_rowA[0][ci], p01 = s_rowA[0][ci + 1];
                const float p10 = s_rowB[0][ci], p11 = s_rowB[0][ci + 1];
                const float n00 = s_rowA[1][ci], n01 = s_rowA[1][ci + 1];
                const float n10 = s_rowB[1][ci], n11 = s_rowB[1][ci + 1];
                const float dxp = 0.25f * (p01 - p00 + p11 - p10);
                const float dxn = 0.25f * (n01 - n00 + n11 - n10);
                const float dyp = 0.25f * (p10 + p11 - p00 - p01);
                const float dyn = 0.25f * (n10 + n11 - n00 - n01);
                const float fx  = 0.5f * (dxp + dxn);
                const float fy  = 0.5f * (dyp + dyn);
                const float ft  = 0.25f * ((n00 + n01 + n10 + n11) -
                                           (p00 + p01 + p10 + p11));
                q0 = fx * fx; q1 = fx * fy; q2 = fy * fy;
                q3 = fx * ft; q4 = fy * ft;
            }
            s_prow[0][ci] = q0; s_prow[1][ci] = q1; s_prow[2][ci] = q2;
            s_prow[3][ci] = q3; s_prow[4][ci] = q4;
        }
        __syncthreads();

        // ---- 15-tap horizontal sums for this thread's output column ----
        float h0 = 0.f, h1 = 0.f, h2 = 0.f, h3 = 0.f, h4 = 0.f;
        #pragma unroll
        for (int k = 0; k < WIN; ++k) {
            h0 += s_prow[0][tid + k];
            h1 += s_prow[1][tid + k];
            h2 += s_prow[2][tid + k];
            h3 += s_prow[3][tid + k];
            h4 += s_prow[4][tid + k];
        }

        // ---- vertical sliding window via ring buffer (thread-private slots) ----
        const int slot = sr % WIN;
        a0 += h0 - s_ring[slot][0][tid]; s_ring[slot][0][tid] = h0;
        a1 += h1 - s_ring[slot][1][tid]; s_ring[slot][1][tid] = h1;
        a2 += h2 - s_ring[slot][2][tid]; s_ring[slot][2][tid] = h2;
        a3 += h3 - s_ring[slot][3][tid]; s_ring[slot][3][tid] = h3;
        a4 += h4 - s_ring[slot][4][tid]; s_ring[slot][4][tid] = h4;

        // ---- emit output row i = pr - RAD once the window is full ----
        if (sr >= WIN - 1) {
            const int i  = pr - RAD;                 // in [r0, r0+RB)
            const float det = a0 * a2 - a1 * a1;
            float u = 0.f, v = 0.f;
            if (det != 0.f) {
                u = (a2 * a3 - a1 * a4) / det;
                v = (a0 * a4 - a1 * a3) / det;
            }
            out[i * IW + x]           = u;
            out[IH * IW + i * IW + x] = v;
        }
        // No barrier needed here: next iteration's first write (s_rowA/B)
        // races with nothing (products phase of this iteration completed
        // before the barrier above; h-reads touch only s_prow, which is
        // rewritten only after the next staging barrier).
        __syncthreads();
    }
}

extern "C" void kernel_launch(void* const* d_in, const int* in_sizes, int n_in,
                              void* d_out, int out_size, void* d_ws, size_t ws_size,
                              hipStream_t stream) {
    (void)in_sizes; (void)n_in; (void)d_ws; (void)ws_size; (void)out_size;
    const float* prev = (const float*)d_in[0];
    const float* nxt  = (const float*)d_in[1];
    float* out        = (float*)d_out;
    dim3 grid(IW / SW, IH / RB);   // 16 x 64 = 1024 blocks
    dim3 block(BT);
    hipLaunchKernelGGL(lk_fused_kernel, grid, block, 0, stream, prev, nxt, out);
}

// Round 2
// 58.375 us; speedup vs baseline: 2.8466x; 2.8466x over previous
//
#include <hip/hip_runtime.h>

// Lucas-Kanade optical flow, fused single kernel, v2.
// Vertical box sum streamed in registers (add entering row, subtract exiting
// row recomputed from global); LDS only holds the 5 V-planes for the
// horizontal 15-tap window. 1 wave per block, 4 output columns per thread.

constexpr int IH  = 2048;
constexpr int IW  = 2048;
constexpr int RAD = 7;
constexpr int WIN = 15;
constexpr int NT  = 64;              // threads per block (1 wave)
constexpr int SW  = 240;             // output columns per block
constexpr int RB  = 18;              // output rows per block
constexpr int NC  = 256;             // tracked product columns (= 4*NT); pc = c0-8+ci
constexpr int SVP = 272;             // padded s_V columns
constexpr int SCAN = RB + WIN - 1;   // 32 scan rows per block

__device__ __forceinline__ int clampi(int v, int lo, int hi) {
    return v < lo ? lo : (v > hi ? hi : v);
}

__device__ __forceinline__ void load_row5(const float* __restrict__ img, int row,
                                          int pcb, bool xedge, float v[5]) {
    const float* rp = img + (size_t)row * IW;
    if (!xedge) {
        const float4 q = *reinterpret_cast<const float4*>(rp + pcb);  // 16B-aligned
        v[0] = q.x; v[1] = q.y; v[2] = q.z; v[3] = q.w;
        v[4] = rp[pcb + 4];
    } else {
        #pragma unroll
        for (int c = 0; c < 5; ++c) {
            const int g = clampi(pcb + c, 0, IW - 1);
            v[c] = rp[g];
        }
    }
}

template<bool ADD>
__device__ __forceinline__ void accum5(float V[5][4],
                                       const float A0[5], const float A1[5],
                                       const float B0[5], const float B1[5],
                                       bool xedge, int pcb) {
    #pragma unroll
    for (int c = 0; c < 4; ++c) {
        const float p00 = A0[c], p01 = A0[c + 1], p10 = A1[c], p11 = A1[c + 1];
        const float n00 = B0[c], n01 = B0[c + 1], n10 = B1[c], n11 = B1[c + 1];
        float fx = 0.125f * ((p01 - p00) + (p11 - p10) + (n01 - n00) + (n11 - n10));
        float fy = 0.125f * ((p10 - p00) + (p11 - p01) + (n10 - n00) + (n11 - n01));
        float ft = 0.25f  * ((n00 + n01 + n10 + n11) - (p00 + p01 + p10 + p11));
        if (xedge) {
            const int pc = pcb + c;
            if (pc < 0 || pc >= IW) { fx = 0.f; fy = 0.f; ft = 0.f; }
        }
        if (ADD) {
            V[0][c] += fx * fx; V[1][c] += fx * fy; V[2][c] += fy * fy;
            V[3][c] += fx * ft; V[4][c] += fy * ft;
        } else {
            V[0][c] -= fx * fx; V[1][c] -= fx * fy; V[2][c] -= fy * fy;
            V[3][c] -= fx * ft; V[4][c] -= fy * ft;
        }
    }
}

__global__ __launch_bounds__(NT)
void lk_kernel(const float* __restrict__ Pimg, const float* __restrict__ Nimg,
               float* __restrict__ out) {
    const int t   = threadIdx.x;
    const int c0  = blockIdx.x * SW;
    const int r0  = blockIdx.y * RB;
    const int ci0 = 4 * t;                  // first owned product column
    const int pcb = c0 - 8 + ci0;           // its global column
    const bool xedge = (c0 == 0) || (c0 - 8 + NC > IW);

    __shared__ float sV[5][SVP];
    for (int k = t; k < 5 * SVP; k += NT) (&sV[0][0])[k] = 0.f;  // incl. pad cols

    float V[5][4];
    #pragma unroll
    for (int p = 0; p < 5; ++p)
        #pragma unroll
        for (int c = 0; c < 4; ++c) V[p][c] = 0.f;

    float inA[2][5], inB[2][5], outAr[2][5], outBr[2][5];
    #pragma unroll
    for (int im = 0; im < 2; ++im)
        #pragma unroll
        for (int c = 0; c < 5; ++c) { outAr[im][c] = 0.f; outBr[im][c] = 0.f; }

    // prologue: inB holds row (r0-RAD); becomes inA at sr=0
    {
        const int rr = clampi(r0 - RAD, 0, IH - 1);
        load_row5(Pimg, rr, pcb, xedge, inB[0]);
        load_row5(Nimg, rr, pcb, xedge, inB[1]);
    }

    for (int sr = 0; sr < SCAN; ++sr) {
        const int pr = r0 - RAD + sr;       // entering product row

        // shift entering-row cache, load row pr+1
        #pragma unroll
        for (int im = 0; im < 2; ++im)
            #pragma unroll
            for (int c = 0; c < 5; ++c) inA[im][c] = inB[im][c];
        {
            const int rr = clampi(pr + 1, 0, IH - 1);
            load_row5(Pimg, rr, pcb, xedge, inB[0]);
            load_row5(Nimg, rr, pcb, xedge, inB[1]);
        }

        // exiting-row cache (rows pr-WIN, pr-WIN+1)
        if (sr >= WIN) {
            #pragma unroll
            for (int im = 0; im < 2; ++im)
                #pragma unroll
                for (int c = 0; c < 5; ++c) outAr[im][c] = outBr[im][c];
        }
        if (sr >= WIN - 1) {
            const int rr = clampi(pr - WIN + 1, 0, IH - 1);
            load_row5(Pimg, rr, pcb, xedge, outBr[0]);
            load_row5(Nimg, rr, pcb, xedge, outBr[1]);
        }

        // vertical running box sum
        if (pr >= 0 && pr < IH)
            accum5<true>(V, inA[0], inB[0], inA[1], inB[1], xedge, pcb);
        const int po = pr - WIN;
        if (sr >= WIN && po >= 0 && po < IH)
            accum5<false>(V, outAr[0], outBr[0], outAr[1], outBr[1], xedge, pcb);

        if (sr >= WIN - 1) {
            // publish V row to LDS
            #pragma unroll
            for (int p = 0; p < 5; ++p) {
                float4 q; q.x = V[p][0]; q.y = V[p][1]; q.z = V[p][2]; q.w = V[p][3];
                *reinterpret_cast<float4*>(&sV[p][ci0]) = q;
            }
            __syncthreads();

            // horizontal 15-tap window sums, 4 outputs per thread
            float a[5][4];
            #pragma unroll
            for (int p = 0; p < 5; ++p) {
                float w[20];
                #pragma unroll
                for (int k = 0; k < 5; ++k) {
                    const float4 q = *reinterpret_cast<const float4*>(&sV[p][ci0 + 4 * k]);
                    w[4 * k] = q.x; w[4 * k + 1] = q.y; w[4 * k + 2] = q.z; w[4 * k + 3] = q.w;
                }
                float s = w[1];
                #pragma unroll
                for (int k = 2; k <= 15; ++k) s += w[k];
                a[p][0] = s;                       // window cols j+1..j+15 (j = ci0)
                s = s - w[1] + w[16]; a[p][1] = s;
                s = s - w[2] + w[17]; a[p][2] = s;
                s = s - w[3] + w[18]; a[p][3] = s;
            }

            const int i = pr - RAD;               // output row
            if (i < IH) {                          // uniform
                float uo[4], vo[4];
                #pragma unroll
                for (int c = 0; c < 4; ++c) {
                    const float Axx = a[0][c], Axy = a[1][c], Ayy = a[2][c];
                    const float bx = a[3][c], by = a[4][c];
                    const float det = Axx * Ayy - Axy * Axy;
                    float u = 0.f, vv = 0.f;
                    if (det != 0.f) {
                        const float rd = 1.0f / det;
                        u  = (Ayy * bx - Axy * by) * rd;
                        vv = (Axx * by - Axy * bx) * rd;
                    }
                    uo[c] = u; vo[c] = vv;
                }
                const int x = c0 + ci0;
                if (ci0 < SW && x < IW) {
                    float4 qu; qu.x = uo[0]; qu.y = uo[1]; qu.z = uo[2]; qu.w = uo[3];
                    float4 qv; qv.x = vo[0]; qv.y = vo[1]; qv.z = vo[2]; qv.w = vo[3];
                    *reinterpret_cast<float4*>(out + (size_t)i * IW + x) = qu;
                    *reinterpret_cast<float4*>(out + (size_t)IH * IW + (size_t)i * IW + x) = qv;
                }
            }
            __syncthreads();
        }
    }
}

extern "C" void kernel_launch(void* const* d_in, const int* in_sizes, int n_in,
                              void* d_out, int out_size, void* d_ws, size_t ws_size,
                              hipStream_t stream) {
    (void)in_sizes; (void)n_in; (void)d_ws; (void)ws_size; (void)out_size;
    const float* prev = (const float*)d_in[0];
    const float* nxt  = (const float*)d_in[1];
    float* out        = (float*)d_out;
    dim3 grid((IW + SW - 1) / SW, (IH + RB - 1) / RB);   // 9 x 114 = 1026 blocks
    dim3 block(NT);
    hipLaunchKernelGGL(lk_kernel, grid, block, 0, stream, prev, nxt, out);
}